// Round 11
// baseline (327.652 us; speedup 1.0000x reference)
//
#include <hip/hip_runtime.h>
#include <hip/hip_bf16.h>

#define NT   32768
#define NH   2048
#define NE   128
#define TOPK 8
#define BT   32
#define SBT  128             // tokens per select block
#define BND    6.0e-4f
#define TWO_B  (2.0f * BND)

// ws layout (bytes):
//   [0,64):          u32 flagged-token counter
//   [64, 64+1MB):    Wt: B-fragment-ordered split-bf16 W (16B chunk g: lane=g&63,
//                    te=(g>>6)&7, s=(g>>9)&1, k32=g>>10)
//   [64+1MB, ...):   records, 32B each: u32 token, u32 cnt, 16x u8 cand ids
#define WS_W_OFF   64
#define WS_REC_U32 262160     // (64 + 1MB)/4

typedef __attribute__((ext_vector_type(8))) short bf16x8;
typedef __attribute__((ext_vector_type(4))) float f32x4;
typedef __attribute__((ext_vector_type(4))) unsigned int u32x4;

static __device__ __forceinline__ unsigned short f2bf(float f) {
    __hip_bfloat16 h = __float2bfloat16(f);
    return *reinterpret_cast<unsigned short*>(&h);
}

// ---------------- K0: build B-fragment-ordered W hi/lo chunks (RNE split) ----------------
__global__ __launch_bounds__(256) void prep_w_kernel(
    const float* __restrict__ W, unsigned short* __restrict__ Wt)
{
    int g = blockIdx.x * 256 + threadIdx.x;   // 65536 16B-per-lane chunks
    int lane = g & 63;
    int te   = (g >> 6) & 7;
    int s    = (g >> 9) & 1;
    int k32  = g >> 10;
    int row  = te * 16 + (lane & 15);
    int kb   = k32 * 32 + (lane >> 4) * 8;
    const float* src = W + (size_t)row * NH + kb;
    float4 f0 = *(const float4*)src;
    float4 f1 = *(const float4*)(src + 4);
    float f[8] = {f0.x, f0.y, f0.z, f0.w, f1.x, f1.y, f1.z, f1.w};
    bf16x8 o;
    #pragma unroll
    for (int e = 0; e < 8; ++e) {
        unsigned short h = f2bf(f[e]);
        if (s == 0) o[e] = (short)h;
        else {
            float fh = __builtin_bit_cast(float, ((unsigned int)h) << 16);
            o[e] = (short)f2bf(f[e] - fh);
        }
    }
    *(bf16x8*)(Wt + (size_t)g * 8) = o;
}

// ---------------- K1: reg-dbuf prefetched split-bf16 MFMA GEMM -> raw logits ----------------
// 256 thr = 4 waves; wave w owns K-slice [w*512, w*512+512); 32 tokens/block.
__global__ __launch_bounds__(256, 2) void router_gemm_kernel(
    const float* __restrict__ X, const unsigned short* __restrict__ Wt,
    float* __restrict__ outLg)
{
    __shared__ float ps[2][BT * 132];   // 33.8 KB

    const int tid  = threadIdx.x;
    const int lane = tid & 63;
    const int w    = tid >> 6;           // 0..3
    const int l15  = lane & 15, lhi = lane >> 4;
    const int t0   = blockIdx.x * BT;

    f32x4 acc[2][8];
    #pragma unroll
    for (int i = 0; i < 2; ++i)
        #pragma unroll
        for (int te = 0; te < 8; ++te) acc[i][te] = (f32x4){0.f, 0.f, 0.f, 0.f};

    const float* x0 = X + (size_t)(t0 + l15) * NH + w * 512 + lhi * 8;
    const float* x1 = x0 + 16 * NH;
    const unsigned short* wbase = Wt + (size_t)(w * 16) * 8192 + lane * 8;

    bf16x8 b0[8][2], b1[8][2];

    #define LOADB(arr, kk) do {                                                \
        const unsigned short* wb_ = wbase + (size_t)(kk) * 8192;               \
        _Pragma("unroll")                                                      \
        for (int te = 0; te < 8; ++te) {                                       \
            arr[te][0] = *(const bf16x8*)(wb_ + te * 512);                     \
            arr[te][1] = *(const bf16x8*)(wb_ + 4096 + te * 512);              \
        }                                                                      \
    } while (0)

    // round-half-up bit-split: ~3.5 VALU/elem; |x-ah-al| <= 2^-18|x|
    #define SPLITA(kk, ah, al) do {                                            \
        _Pragma("unroll")                                                      \
        for (int i = 0; i < 2; ++i) {                                          \
            const float* xp = (i ? x1 : x0) + (kk) * 32;                       \
            float4 fa = *(const float4*)xp;                                    \
            float4 fb = *(const float4*)(xp + 4);                              \
            float ff[8] = {fa.x, fa.y, fa.z, fa.w, fb.x, fb.y, fb.z, fb.w};    \
            unsigned int hu[4], lu[4];                                         \
            _Pragma("unroll")                                                  \
            for (int p = 0; p < 4; ++p) {                                      \
                unsigned int u0 = __builtin_bit_cast(unsigned int, ff[2*p]);   \
                unsigned int u1 = __builtin_bit_cast(unsigned int, ff[2*p+1]); \
                unsigned int r0 = u0 + 0x8000u, r1 = u1 + 0x8000u;             \
                hu[p] = (r0 >> 16) | (r1 & 0xFFFF0000u);                       \
                float h0 = __builtin_bit_cast(float, r0 & 0xFFFF0000u);        \
                float h1 = __builtin_bit_cast(float, r1 & 0xFFFF0000u);        \
                float e0 = ff[2*p] - h0, e1 = ff[2*p+1] - h1;                  \
                unsigned int s0 = __builtin_bit_cast(unsigned int, e0) + 0x8000u; \
                unsigned int s1 = __builtin_bit_cast(unsigned int, e1) + 0x8000u; \
                lu[p] = (s0 >> 16) | (s1 & 0xFFFF0000u);                       \
            }                                                                  \
            ah[i] = __builtin_bit_cast(bf16x8, (u32x4){hu[0],hu[1],hu[2],hu[3]}); \
            al[i] = __builtin_bit_cast(bf16x8, (u32x4){lu[0],lu[1],lu[2],lu[3]}); \
        }                                                                      \
    } while (0)

    #define DOMFMA(b, ah, al) do {                                             \
        _Pragma("unroll")                                                      \
        for (int te = 0; te < 8; ++te) {                                       \
            acc[0][te] = __builtin_amdgcn_mfma_f32_16x16x32_bf16(ah[0], b[te][0], acc[0][te], 0, 0, 0); \
            acc[1][te] = __builtin_amdgcn_mfma_f32_16x16x32_bf16(ah[1], b[te][0], acc[1][te], 0, 0, 0); \
            acc[0][te] = __builtin_amdgcn_mfma_f32_16x16x32_bf16(al[0], b[te][0], acc[0][te], 0, 0, 0); \
            acc[1][te] = __builtin_amdgcn_mfma_f32_16x16x32_bf16(al[1], b[te][0], acc[1][te], 0, 0, 0); \
            acc[0][te] = __builtin_amdgcn_mfma_f32_16x16x32_bf16(ah[0], b[te][1], acc[0][te], 0, 0, 0); \
            acc[1][te] = __builtin_amdgcn_mfma_f32_16x16x32_bf16(ah[1], b[te][1], acc[1][te], 0, 0, 0); \
        }                                                                      \
    } while (0)

    LOADB(b0, 0);
    for (int p = 0; p < 8; ++p) {
        bf16x8 ah[2], al[2];
        LOADB(b1, 2 * p + 1);
        SPLITA(2 * p, ah, al);
        DOMFMA(b0, ah, al);
        if (p < 7) LOADB(b0, 2 * p + 2);
        SPLITA(2 * p + 1, ah, al);
        DOMFMA(b1, ah, al);
    }

    // ---- cross-wave K reduction ----
    if (w < 2) {
        #pragma unroll
        for (int i = 0; i < 2; ++i)
            #pragma unroll
            for (int te = 0; te < 8; ++te)
                #pragma unroll
                for (int q = 0; q < 4; ++q)
                    ps[w][(i * 16 + lhi * 4 + q) * 132 + te * 16 + l15] = acc[i][te][q];
    }
    __syncthreads();
    if (w >= 2) {
        #pragma unroll
        for (int i = 0; i < 2; ++i)
            #pragma unroll
            for (int te = 0; te < 8; ++te)
                #pragma unroll
                for (int q = 0; q < 4; ++q) {
                    int o = (i * 16 + lhi * 4 + q) * 132 + te * 16 + l15;
                    ps[w - 2][o] += acc[i][te][q];
                }
    }
    __syncthreads();
    // fold + coalesced store of raw f32 logits into the out scores region
    #pragma unroll
    for (int q = 0; q < 4; ++q) {
        int i = tid + q * 256;                 // 0..1023
        int row = i >> 5, c4 = i & 31;
        int o = row * 132 + c4 * 4;
        float4 a = *(float4*)&ps[0][o];
        float4 b = *(float4*)&ps[1][o];
        a.x += b.x; a.y += b.y; a.z += b.z; a.w += b.w;
        *(float4*)(outLg + (size_t)(t0 + row) * NE + c4 * 4) = a;
    }
}

// ---------------- K2: LDS-staged select with block-aggregated flag atomics ----------------
__global__ __launch_bounds__(512) void select_kernel(
    float* __restrict__ out, unsigned int* __restrict__ ws)
{
    __shared__ float lg[SBT * 132];          // 66 KB
    __shared__ unsigned int wcnt[2];
    __shared__ unsigned int blkbase;

    const int tid  = threadIdx.x;
    const int lane = tid & 63;
    const int wv   = tid >> 6;
    const int t0   = blockIdx.x * SBT;

    // stage: 128 rows x 32 float4, fully coalesced
    #pragma unroll
    for (int q = 0; q < 8; ++q) {
        int i = tid + q * 512;
        int row = i >> 5, c4 = i & 31;
        float4 v = *(const float4*)(out + (size_t)(t0 + row) * NE + c4 * 4);
        *(float4*)(&lg[row * 132 + c4 * 4]) = v;
    }
    __syncthreads();

    float pv[8]; int ti[13]; bool flag = false; float ksum = 0.f;
    unsigned int cnt = 0;
    unsigned long long pk0 = 0ull, pk1 = 0ull;   // packed candidate ids (scratch-free)
    unsigned int myrank = 0;

    if (tid < SBT) {
        const float* row = &lg[tid * 132];
        float tv[13];
        #pragma unroll
        for (int k = 0; k < 13; ++k) { tv[k] = -3.0e38f; ti[k] = 0; }
        #pragma unroll 4
        for (int e = 0; e < NE; ++e) {
            float v = row[e];
            if (v > tv[12]) {
                float cv = v; int ci = e;
                #pragma unroll
                for (int s = 0; s < 13; ++s) {
                    if (cv > tv[s]) {
                        float t1 = tv[s]; int t2 = ti[s];
                        tv[s] = cv; ti[s] = ci; cv = t1; ci = t2;
                    }
                }
            }
        }
        #pragma unroll
        for (int k = 0; k < 8; ++k) flag |= (tv[k] - tv[k + 1] < TWO_B);
        #pragma unroll
        for (int k = 0; k < 8; ++k) { pv[k] = expf(tv[k] - tv[0]); ksum += pv[k]; }

        if (flag) {
            float thr = tv[7] - TWO_B;
            if (tv[12] >= thr) {
                cnt = 0xFFu;
            } else {
                #pragma unroll
                for (int k = 0; k < 13; ++k) {
                    if (k < 8 || tv[k] >= thr) {
                        unsigned long long b = (unsigned long long)(unsigned int)ti[k];
                        if (cnt < 8) pk0 |= b << (8 * cnt);
                        else         pk1 |= b << (8 * (cnt - 8));
                        ++cnt;
                    }
                }
            }
        }
        // per-wave aggregation of flags (waves 0,1 only; wave-uniform branch)
        unsigned long long m = __ballot(flag);
        myrank = (unsigned int)__popcll(m & ((1ull << lane) - 1ull));
        if (lane == 0) wcnt[wv] = (unsigned int)__popcll(m);
    }
    __syncthreads();
    if (tid == 0) {
        unsigned int tot = wcnt[0] + wcnt[1];
        blkbase = tot ? atomicAdd(ws, tot) : 0u;
    }
    __syncthreads();   // blkbase ready; LDS reads done -> safe to overwrite out

    // cooperative zero of this block's 128 dense rows (4096 float4)
    float* scoreBase = out + (size_t)t0 * NE;
    #pragma unroll
    for (int q = 0; q < 8; ++q) {
        int i = tid + q * 512;
        *(float4*)(scoreBase + (size_t)i * 4) = make_float4(0.f, 0.f, 0.f, 0.f);
    }
    __syncthreads();   // zeros complete before owner scatter

    if (tid < SBT) {
        const int tg = t0 + tid;
        float* srow = out + (size_t)tg * NE;
        float* irow = out + (size_t)NT * NE + (size_t)tg * TOPK;
        #pragma unroll
        for (int k = 0; k < 8; ++k) srow[ti[k]] = pv[k] / ksum;
        float4 i0 = make_float4((float)ti[0], (float)ti[1], (float)ti[2], (float)ti[3]);
        float4 i1 = make_float4((float)ti[4], (float)ti[5], (float)ti[6], (float)ti[7]);
        *(float4*)irow = i0;
        *(float4*)(irow + 4) = i1;

        if (flag) {
            unsigned int slot = blkbase + (wv ? wcnt[0] : 0u) + myrank;
            unsigned int* rec = ws + WS_REC_U32 + slot * 8;
            rec[0] = (unsigned int)tg;
            rec[1] = cnt;
            rec[2] = (unsigned int)pk0;
            rec[3] = (unsigned int)(pk0 >> 32);
            rec[4] = (unsigned int)pk1;
            rec[5] = (unsigned int)(pk1 >> 32);
        }
    }
}

// ---------------- K3: f64 refine flagged tokens ----------------
__global__ __launch_bounds__(256) void finalize_kernel(
    const float* __restrict__ X, const float* __restrict__ W,
    float* __restrict__ out, const unsigned int* __restrict__ ws)
{
    __shared__ float  xs[2048];
    __shared__ double cv[128];
    __shared__ int    cid[128];
    __shared__ float  ovals[8];
    __shared__ int    oidx[8];

    const int tid = threadIdx.x;
    const int lane = tid & 63, w = tid >> 6;
    const unsigned int n = ws[0];

    for (unsigned int rI = blockIdx.x; rI < n; rI += gridDim.x) {
        const unsigned int* rec = ws + WS_REC_U32 + rI * 8;
        const int tg = (int)rec[0];
        const unsigned int cnt = rec[1];
        const unsigned char* ids = (const unsigned char*)(rec + 2);
        const int nc = (cnt == 0xFFu) ? NE : (int)cnt;

        #pragma unroll
        for (int q = 0; q < 2; ++q) {
            int i = tid + q * 256;
            *(float4*)(xs + i * 4) = *(const float4*)(X + (size_t)tg * NH + i * 4);
        }
        __syncthreads();

        for (int c = w; c < nc; c += 4) {
            int e = (cnt == 0xFFu) ? c : (int)ids[c];
            const float* wrow = W + (size_t)e * NH;
            double s = 0.0;
            #pragma unroll
            for (int m = 0; m < 8; ++m) {
                float4 wv = *(const float4*)(wrow + m * 256 + lane * 4);
                float4 xv = *(const float4*)(xs + m * 256 + lane * 4);
                s = fma((double)xv.x, (double)wv.x, s);
                s = fma((double)xv.y, (double)wv.y, s);
                s = fma((double)xv.z, (double)wv.z, s);
                s = fma((double)xv.w, (double)wv.w, s);
            }
            #pragma unroll
            for (int off = 32; off >= 1; off >>= 1) s += __shfl_xor(s, off);
            if (lane == 0) { cv[c] = s; cid[c] = e; }
        }
        __syncthreads();

        if (tid == 0) {
            double lv[8];
            #pragma unroll
            for (int k = 0; k < 8; ++k) {
                double best = -1.0e300; int bi = 1 << 30, bc = 0;
                for (int c = 0; c < nc; ++c) {
                    double v = cv[c]; int e = cid[c];
                    if (v > best || (v == best && e < bi)) { best = v; bi = e; bc = c; }
                }
                lv[k] = best; oidx[k] = bi; cv[bc] = -1.0e301;
            }
            double m = lv[0], sum = 0.0, p[8];
            #pragma unroll
            for (int k = 0; k < 8; ++k) { p[k] = exp(lv[k] - m); sum += p[k]; }
            #pragma unroll
            for (int k = 0; k < 8; ++k) ovals[k] = (float)(p[k] / sum);
        }
        __syncthreads();

        float* srow = out + (size_t)tg * NE;
        if (tid < NE) {
            float val = 0.f;
            #pragma unroll
            for (int k = 0; k < 8; ++k) if (oidx[k] == tid) val = ovals[k];
            srow[tid] = val;
        }
        if (tid < TOPK) out[(size_t)NT * NE + (size_t)tg * TOPK + tid] = (float)oidx[tid];
        __syncthreads();
    }
}

extern "C" void kernel_launch(void* const* d_in, const int* in_sizes, int n_in,
                              void* d_out, int out_size, void* d_ws, size_t ws_size,
                              hipStream_t stream) {
    const float* X = (const float*)d_in[0];
    const float* W = (const float*)d_in[1];
    float* out = (float*)d_out;
    unsigned char* wsb = (unsigned char*)d_ws;
    unsigned short* Wt = (unsigned short*)(wsb + WS_W_OFF);

    hipMemsetAsync(d_ws, 0, 64, stream);
    prep_w_kernel<<<256, 256, 0, stream>>>(W, Wt);
    router_gemm_kernel<<<NT / BT, 256, 0, stream>>>(X, Wt, out);
    select_kernel<<<NT / SBT, 512, 0, stream>>>(out, (unsigned int*)d_ws);
    finalize_kernel<<<1024, 256, 0, stream>>>(X, W, out, (const unsigned int*)d_ws);
}

// Round 12
// 324.042 us; speedup vs baseline: 1.0111x; 1.0111x over previous
//
#include <hip/hip_runtime.h>
#include <hip/hip_bf16.h>

#define NT   32768
#define NH   2048
#define NE   128
#define TOPK 8
#define BT   32
#define SBT  128             // tokens per select block
#define BND    6.0e-4f
#define TWO_B  (2.0f * BND)

// ws layout (bytes):
//   [0,64):          u32 flagged-token counter
//   [64, 64+1MB):    Wt: B-fragment-ordered split-bf16 W (16B chunk g: lane=g&63,
//                    te=(g>>6)&7, s=(g>>9)&1, k32=g>>10)
//   [64+1MB, ...):   records, 32B each: u32 token, u32 cnt, 16x u8 cand ids
#define WS_W_OFF   64
#define WS_REC_U32 262160     // (64 + 1MB)/4

typedef __attribute__((ext_vector_type(8))) short bf16x8;
typedef __attribute__((ext_vector_type(4))) float f32x4;
typedef __attribute__((ext_vector_type(4))) unsigned int u32x4;

static __device__ __forceinline__ unsigned short f2bf(float f) {
    __hip_bfloat16 h = __float2bfloat16(f);
    return *reinterpret_cast<unsigned short*>(&h);
}

// ---------------- K0: build B-fragment-ordered W hi/lo chunks (RNE split) ----------------
__global__ __launch_bounds__(256) void prep_w_kernel(
    const float* __restrict__ W, unsigned short* __restrict__ Wt)
{
    int g = blockIdx.x * 256 + threadIdx.x;   // 65536 16B-per-lane chunks
    int lane = g & 63;
    int te   = (g >> 6) & 7;
    int s    = (g >> 9) & 1;
    int k32  = g >> 10;
    int row  = te * 16 + (lane & 15);
    int kb   = k32 * 32 + (lane >> 4) * 8;
    const float* src = W + (size_t)row * NH + kb;
    float4 f0 = *(const float4*)src;
    float4 f1 = *(const float4*)(src + 4);
    float f[8] = {f0.x, f0.y, f0.z, f0.w, f1.x, f1.y, f1.z, f1.w};
    bf16x8 o;
    #pragma unroll
    for (int e = 0; e < 8; ++e) {
        unsigned short h = f2bf(f[e]);
        if (s == 0) o[e] = (short)h;
        else {
            float fh = __builtin_bit_cast(float, ((unsigned int)h) << 16);
            o[e] = (short)f2bf(f[e] - fh);
        }
    }
    *(bf16x8*)(Wt + (size_t)g * 8) = o;
}

// ---------------- K1: reg-dbuf prefetched split-bf16 MFMA GEMM -> raw logits ----------------
// 256 thr = 4 waves; wave w owns K-slice [w*512, w*512+512); 32 tokens/block.
__global__ __launch_bounds__(256, 2) void router_gemm_kernel(
    const float* __restrict__ X, const unsigned short* __restrict__ Wt,
    float* __restrict__ outLg)
{
    __shared__ float ps[2][BT * 132];   // 33.8 KB

    const int tid  = threadIdx.x;
    const int lane = tid & 63;
    const int w    = tid >> 6;           // 0..3
    const int l15  = lane & 15, lhi = lane >> 4;
    const int t0   = blockIdx.x * BT;

    f32x4 acc[2][8];
    #pragma unroll
    for (int i = 0; i < 2; ++i)
        #pragma unroll
        for (int te = 0; te < 8; ++te) acc[i][te] = (f32x4){0.f, 0.f, 0.f, 0.f};

    const float* x0 = X + (size_t)(t0 + l15) * NH + w * 512 + lhi * 8;
    const float* x1 = x0 + 16 * NH;
    const unsigned short* wbase = Wt + (size_t)(w * 16) * 8192 + lane * 8;

    bf16x8 b0[8][2], b1[8][2];

    #define LOADB(arr, kk) do {                                                \
        const unsigned short* wb_ = wbase + (size_t)(kk) * 8192;               \
        _Pragma("unroll")                                                      \
        for (int te = 0; te < 8; ++te) {                                       \
            arr[te][0] = *(const bf16x8*)(wb_ + te * 512);                     \
            arr[te][1] = *(const bf16x8*)(wb_ + 4096 + te * 512);              \
        }                                                                      \
    } while (0)

    // round-half-up bit-split: ~3.5 VALU/elem; |x-ah-al| <= 2^-18|x|
    #define SPLITA(kk, ah, al) do {                                            \
        _Pragma("unroll")                                                      \
        for (int i = 0; i < 2; ++i) {                                          \
            const float* xp = (i ? x1 : x0) + (kk) * 32;                       \
            float4 fa = *(const float4*)xp;                                    \
            float4 fb = *(const float4*)(xp + 4);                              \
            float ff[8] = {fa.x, fa.y, fa.z, fa.w, fb.x, fb.y, fb.z, fb.w};    \
            unsigned int hu[4], lu[4];                                         \
            _Pragma("unroll")                                                  \
            for (int p = 0; p < 4; ++p) {                                      \
                unsigned int u0 = __builtin_bit_cast(unsigned int, ff[2*p]);   \
                unsigned int u1 = __builtin_bit_cast(unsigned int, ff[2*p+1]); \
                unsigned int r0 = u0 + 0x8000u, r1 = u1 + 0x8000u;             \
                hu[p] = (r0 >> 16) | (r1 & 0xFFFF0000u);                       \
                float h0 = __builtin_bit_cast(float, r0 & 0xFFFF0000u);        \
                float h1 = __builtin_bit_cast(float, r1 & 0xFFFF0000u);        \
                float e0 = ff[2*p] - h0, e1 = ff[2*p+1] - h1;                  \
                unsigned int s0 = __builtin_bit_cast(unsigned int, e0) + 0x8000u; \
                unsigned int s1 = __builtin_bit_cast(unsigned int, e1) + 0x8000u; \
                lu[p] = (s0 >> 16) | (s1 & 0xFFFF0000u);                       \
            }                                                                  \
            ah[i] = __builtin_bit_cast(bf16x8, (u32x4){hu[0],hu[1],hu[2],hu[3]}); \
            al[i] = __builtin_bit_cast(bf16x8, (u32x4){lu[0],lu[1],lu[2],lu[3]}); \
        }                                                                      \
    } while (0)

    #define DOMFMA(b, ah, al) do {                                             \
        _Pragma("unroll")                                                      \
        for (int te = 0; te < 8; ++te) {                                       \
            acc[0][te] = __builtin_amdgcn_mfma_f32_16x16x32_bf16(ah[0], b[te][0], acc[0][te], 0, 0, 0); \
            acc[1][te] = __builtin_amdgcn_mfma_f32_16x16x32_bf16(ah[1], b[te][0], acc[1][te], 0, 0, 0); \
            acc[0][te] = __builtin_amdgcn_mfma_f32_16x16x32_bf16(al[0], b[te][0], acc[0][te], 0, 0, 0); \
            acc[1][te] = __builtin_amdgcn_mfma_f32_16x16x32_bf16(al[1], b[te][0], acc[1][te], 0, 0, 0); \
            acc[0][te] = __builtin_amdgcn_mfma_f32_16x16x32_bf16(ah[0], b[te][1], acc[0][te], 0, 0, 0); \
            acc[1][te] = __builtin_amdgcn_mfma_f32_16x16x32_bf16(ah[1], b[te][1], acc[1][te], 0, 0, 0); \
        }                                                                      \
    } while (0)

    LOADB(b0, 0);
    for (int p = 0; p < 8; ++p) {
        bf16x8 ah[2], al[2];
        LOADB(b1, 2 * p + 1);
        SPLITA(2 * p, ah, al);
        DOMFMA(b0, ah, al);
        if (p < 7) LOADB(b0, 2 * p + 2);
        SPLITA(2 * p + 1, ah, al);
        DOMFMA(b1, ah, al);
    }

    // ---- cross-wave K reduction ----
    if (w < 2) {
        #pragma unroll
        for (int i = 0; i < 2; ++i)
            #pragma unroll
            for (int te = 0; te < 8; ++te)
                #pragma unroll
                for (int q = 0; q < 4; ++q)
                    ps[w][(i * 16 + lhi * 4 + q) * 132 + te * 16 + l15] = acc[i][te][q];
    }
    __syncthreads();
    if (w >= 2) {
        #pragma unroll
        for (int i = 0; i < 2; ++i)
            #pragma unroll
            for (int te = 0; te < 8; ++te)
                #pragma unroll
                for (int q = 0; q < 4; ++q) {
                    int o = (i * 16 + lhi * 4 + q) * 132 + te * 16 + l15;
                    ps[w - 2][o] += acc[i][te][q];
                }
    }
    __syncthreads();
    // fold + coalesced store of raw f32 logits into the out scores region
    #pragma unroll
    for (int q = 0; q < 4; ++q) {
        int i = tid + q * 256;                 // 0..1023
        int row = i >> 5, c4 = i & 31;
        int o = row * 132 + c4 * 4;
        float4 a = *(float4*)&ps[0][o];
        float4 b = *(float4*)&ps[1][o];
        a.x += b.x; a.y += b.y; a.z += b.z; a.w += b.w;
        *(float4*)(outLg + (size_t)(t0 + row) * NE + c4 * 4) = a;
    }
}

// ---------------- K2: LDS-staged select (register-resident arrays: lb(512,2)) ----------------
__global__ __launch_bounds__(512, 2) void select_kernel(
    float* __restrict__ out, unsigned int* __restrict__ ws)
{
    __shared__ float lg[SBT * 132];     // 66 KB

    const int tid = threadIdx.x;
    const int t0  = blockIdx.x * SBT;

    // stage: 128 rows x 32 float4, fully coalesced
    #pragma unroll
    for (int q = 0; q < 8; ++q) {
        int i = tid + q * 512;
        int row = i >> 5, c4 = i & 31;
        float4 v = *(const float4*)(out + (size_t)(t0 + row) * NE + c4 * 4);
        *(float4*)(&lg[row * 132 + c4 * 4]) = v;
    }
    __syncthreads();

    float pv[8]; int ti[13]; bool flag = false; float ksum = 0.f;
    unsigned int cnt = 0;
    unsigned long long pk0 = 0ull, pk1 = 0ull;   // packed candidate ids (scratch-free)

    if (tid < SBT) {
        const float* row = &lg[tid * 132];
        float tv[13];
        #pragma unroll
        for (int k = 0; k < 13; ++k) { tv[k] = -3.0e38f; ti[k] = 0; }
        #pragma unroll 4
        for (int e = 0; e < NE; ++e) {
            float v = row[e];
            if (v > tv[12]) {
                float cv = v; int ci = e;
                #pragma unroll
                for (int s = 0; s < 13; ++s) {
                    if (cv > tv[s]) {
                        float t1 = tv[s]; int t2 = ti[s];
                        tv[s] = cv; ti[s] = ci; cv = t1; ci = t2;
                    }
                }
            }
        }
        #pragma unroll
        for (int k = 0; k < 8; ++k) flag |= (tv[k] - tv[k + 1] < TWO_B);
        #pragma unroll
        for (int k = 0; k < 8; ++k) { pv[k] = expf(tv[k] - tv[0]); ksum += pv[k]; }

        if (flag) {
            float thr = tv[7] - TWO_B;
            if (tv[12] >= thr) {
                cnt = 0xFFu;
            } else {
                #pragma unroll
                for (int k = 0; k < 13; ++k) {
                    if (k < 8 || tv[k] >= thr) {
                        unsigned long long b = (unsigned long long)(unsigned int)ti[k];
                        if (cnt < 8) pk0 |= b << (8 * cnt);
                        else         pk1 |= b << (8 * (cnt - 8));
                        ++cnt;
                    }
                }
            }
        }
    }
    __syncthreads();   // all LDS reads done; safe to overwrite out rows

    // cooperative zero of this block's 128 dense rows (4096 float4)
    float* scoreBase = out + (size_t)t0 * NE;
    #pragma unroll
    for (int q = 0; q < 8; ++q) {
        int i = tid + q * 512;
        *(float4*)(scoreBase + (size_t)i * 4) = make_float4(0.f, 0.f, 0.f, 0.f);
    }
    __syncthreads();   // zeros complete before owner scatter

    if (tid < SBT) {
        const int tg = t0 + tid;
        float* srow = out + (size_t)tg * NE;
        float* irow = out + (size_t)NT * NE + (size_t)tg * TOPK;
        #pragma unroll
        for (int k = 0; k < 8; ++k) srow[ti[k]] = pv[k] / ksum;
        float4 i0 = make_float4((float)ti[0], (float)ti[1], (float)ti[2], (float)ti[3]);
        float4 i1 = make_float4((float)ti[4], (float)ti[5], (float)ti[6], (float)ti[7]);
        *(float4*)irow = i0;
        *(float4*)(irow + 4) = i1;

        if (flag) {
            unsigned int slot = atomicAdd(ws, 1u);
            unsigned int* rec = ws + WS_REC_U32 + slot * 8;
            rec[0] = (unsigned int)tg;
            rec[1] = cnt;
            rec[2] = (unsigned int)pk0;
            rec[3] = (unsigned int)(pk0 >> 32);
            rec[4] = (unsigned int)pk1;
            rec[5] = (unsigned int)(pk1 >> 32);
        }
    }
}

// ---------------- K3: f64 refine flagged tokens ----------------
__global__ __launch_bounds__(256) void finalize_kernel(
    const float* __restrict__ X, const float* __restrict__ W,
    float* __restrict__ out, const unsigned int* __restrict__ ws)
{
    __shared__ float  xs[2048];
    __shared__ double cv[128];
    __shared__ int    cid[128];
    __shared__ float  ovals[8];
    __shared__ int    oidx[8];

    const int tid = threadIdx.x;
    const int lane = tid & 63, w = tid >> 6;
    const unsigned int n = ws[0];

    for (unsigned int rI = blockIdx.x; rI < n; rI += gridDim.x) {
        const unsigned int* rec = ws + WS_REC_U32 + rI * 8;
        const int tg = (int)rec[0];
        const unsigned int cnt = rec[1];
        const unsigned char* ids = (const unsigned char*)(rec + 2);
        const int nc = (cnt == 0xFFu) ? NE : (int)cnt;

        #pragma unroll
        for (int q = 0; q < 2; ++q) {
            int i = tid + q * 256;
            *(float4*)(xs + i * 4) = *(const float4*)(X + (size_t)tg * NH + i * 4);
        }
        __syncthreads();

        for (int c = w; c < nc; c += 4) {
            int e = (cnt == 0xFFu) ? c : (int)ids[c];
            const float* wrow = W + (size_t)e * NH;
            double s = 0.0;
            #pragma unroll
            for (int m = 0; m < 8; ++m) {
                float4 wv = *(const float4*)(wrow + m * 256 + lane * 4);
                float4 xv = *(const float4*)(xs + m * 256 + lane * 4);
                s = fma((double)xv.x, (double)wv.x, s);
                s = fma((double)xv.y, (double)wv.y, s);
                s = fma((double)xv.z, (double)wv.z, s);
                s = fma((double)xv.w, (double)wv.w, s);
            }
            #pragma unroll
            for (int off = 32; off >= 1; off >>= 1) s += __shfl_xor(s, off);
            if (lane == 0) { cv[c] = s; cid[c] = e; }
        }
        __syncthreads();

        if (tid == 0) {
            double lv[8];
            #pragma unroll
            for (int k = 0; k < 8; ++k) {
                double best = -1.0e300; int bi = 1 << 30, bc = 0;
                for (int c = 0; c < nc; ++c) {
                    double v = cv[c]; int e = cid[c];
                    if (v > best || (v == best && e < bi)) { best = v; bi = e; bc = c; }
                }
                lv[k] = best; oidx[k] = bi; cv[bc] = -1.0e301;
            }
            double m = lv[0], sum = 0.0, p[8];
            #pragma unroll
            for (int k = 0; k < 8; ++k) { p[k] = exp(lv[k] - m); sum += p[k]; }
            #pragma unroll
            for (int k = 0; k < 8; ++k) ovals[k] = (float)(p[k] / sum);
        }
        __syncthreads();

        float* srow = out + (size_t)tg * NE;
        if (tid < NE) {
            float val = 0.f;
            #pragma unroll
            for (int k = 0; k < 8; ++k) if (oidx[k] == tid) val = ovals[k];
            srow[tid] = val;
        }
        if (tid < TOPK) out[(size_t)NT * NE + (size_t)tg * TOPK + tid] = (float)oidx[tid];
        __syncthreads();
    }
}

extern "C" void kernel_launch(void* const* d_in, const int* in_sizes, int n_in,
                              void* d_out, int out_size, void* d_ws, size_t ws_size,
                              hipStream_t stream) {
    const float* X = (const float*)d_in[0];
    const float* W = (const float*)d_in[1];
    float* out = (float*)d_out;
    unsigned char* wsb = (unsigned char*)d_ws;
    unsigned short* Wt = (unsigned short*)(wsb + WS_W_OFF);

    hipMemsetAsync(d_ws, 0, 64, stream);
    prep_w_kernel<<<256, 256, 0, stream>>>(W, Wt);
    router_gemm_kernel<<<NT / BT, 256, 0, stream>>>(X, Wt, out);
    select_kernel<<<NT / SBT, 512, 0, stream>>>(out, (unsigned int*)d_ws);
    finalize_kernel<<<1024, 256, 0, stream>>>(X, W, out, (const unsigned int*)d_ws);
}

// Round 13
// 236.475 us; speedup vs baseline: 1.3856x; 1.3703x over previous
//
#include <hip/hip_runtime.h>
#include <hip/hip_bf16.h>

#define NT   32768
#define NH   2048
#define NE   128
#define TOPK 8
#define BT   32
#define BND    6.0e-4f
#define TWO_B  (2.0f * BND)

// ws layout (bytes):
//   [0,64):          u32 flagged-token counter
//   [64, 64+1MB):    Wt: B-fragment-ordered split-bf16 W (16B chunk g: lane=g&63,
//                    te=(g>>6)&7, s=(g>>9)&1, k32=g>>10)
//   [64+1MB, ...):   records, 32B each: u32 token, u32 cnt, 16x u8 cand ids
#define WS_W_OFF   64
#define WS_REC_U32 262160     // (64 + 1MB)/4

typedef __attribute__((ext_vector_type(8))) short bf16x8;
typedef __attribute__((ext_vector_type(4))) float f32x4;
typedef __attribute__((ext_vector_type(4))) unsigned int u32x4;

static __device__ __forceinline__ unsigned short f2bf(float f) {
    __hip_bfloat16 h = __float2bfloat16(f);
    return *reinterpret_cast<unsigned short*>(&h);
}

// ---------------- K0: build B-fragment-ordered W hi/lo chunks (RNE split) ----------------
__global__ __launch_bounds__(256) void prep_w_kernel(
    const float* __restrict__ W, unsigned short* __restrict__ Wt)
{
    int g = blockIdx.x * 256 + threadIdx.x;   // 65536 16B-per-lane chunks
    int lane = g & 63;
    int te   = (g >> 6) & 7;
    int s    = (g >> 9) & 1;
    int k32  = g >> 10;
    int row  = te * 16 + (lane & 15);
    int kb   = k32 * 32 + (lane >> 4) * 8;
    const float* src = W + (size_t)row * NH + kb;
    float4 f0 = *(const float4*)src;
    float4 f1 = *(const float4*)(src + 4);
    float f[8] = {f0.x, f0.y, f0.z, f0.w, f1.x, f1.y, f1.z, f1.w};
    bf16x8 o;
    #pragma unroll
    for (int e = 0; e < 8; ++e) {
        unsigned short h = f2bf(f[e]);
        if (s == 0) o[e] = (short)h;
        else {
            float fh = __builtin_bit_cast(float, ((unsigned int)h) << 16);
            o[e] = (short)f2bf(f[e] - fh);
        }
    }
    *(bf16x8*)(Wt + (size_t)g * 8) = o;
}

// ---------------- K1: reg-dbuf prefetched split-bf16 MFMA GEMM -> raw logits ----------------
// 256 thr = 4 waves; wave w owns K-slice [w*512, w*512+512); 32 tokens/block.
__global__ __launch_bounds__(256, 2) void router_gemm_kernel(
    const float* __restrict__ X, const unsigned short* __restrict__ Wt,
    float* __restrict__ outLg)
{
    __shared__ float ps[2][BT * 132];   // 33.8 KB

    const int tid  = threadIdx.x;
    const int lane = tid & 63;
    const int w    = tid >> 6;           // 0..3
    const int l15  = lane & 15, lhi = lane >> 4;
    const int t0   = blockIdx.x * BT;

    f32x4 acc[2][8];
    #pragma unroll
    for (int i = 0; i < 2; ++i)
        #pragma unroll
        for (int te = 0; te < 8; ++te) acc[i][te] = (f32x4){0.f, 0.f, 0.f, 0.f};

    const float* x0 = X + (size_t)(t0 + l15) * NH + w * 512 + lhi * 8;
    const float* x1 = x0 + 16 * NH;
    const unsigned short* wbase = Wt + (size_t)(w * 16) * 8192 + lane * 8;

    bf16x8 b0[8][2], b1[8][2];

    #define LOADB(arr, kk) do {                                                \
        const unsigned short* wb_ = wbase + (size_t)(kk) * 8192;               \
        _Pragma("unroll")                                                      \
        for (int te = 0; te < 8; ++te) {                                       \
            arr[te][0] = *(const bf16x8*)(wb_ + te * 512);                     \
            arr[te][1] = *(const bf16x8*)(wb_ + 4096 + te * 512);              \
        }                                                                      \
    } while (0)

    // round-half-up bit-split: ~3.5 VALU/elem; |x-ah-al| <= 2^-18|x|
    #define SPLITA(kk, ah, al) do {                                            \
        _Pragma("unroll")                                                      \
        for (int i = 0; i < 2; ++i) {                                          \
            const float* xp = (i ? x1 : x0) + (kk) * 32;                       \
            float4 fa = *(const float4*)xp;                                    \
            float4 fb = *(const float4*)(xp + 4);                              \
            float ff[8] = {fa.x, fa.y, fa.z, fa.w, fb.x, fb.y, fb.z, fb.w};    \
            unsigned int hu[4], lu[4];                                         \
            _Pragma("unroll")                                                  \
            for (int p = 0; p < 4; ++p) {                                      \
                unsigned int u0 = __builtin_bit_cast(unsigned int, ff[2*p]);   \
                unsigned int u1 = __builtin_bit_cast(unsigned int, ff[2*p+1]); \
                unsigned int r0 = u0 + 0x8000u, r1 = u1 + 0x8000u;             \
                hu[p] = (r0 >> 16) | (r1 & 0xFFFF0000u);                       \
                float h0 = __builtin_bit_cast(float, r0 & 0xFFFF0000u);        \
                float h1 = __builtin_bit_cast(float, r1 & 0xFFFF0000u);        \
                float e0 = ff[2*p] - h0, e1 = ff[2*p+1] - h1;                  \
                unsigned int s0 = __builtin_bit_cast(unsigned int, e0) + 0x8000u; \
                unsigned int s1 = __builtin_bit_cast(unsigned int, e1) + 0x8000u; \
                lu[p] = (s0 >> 16) | (s1 & 0xFFFF0000u);                       \
            }                                                                  \
            ah[i] = __builtin_bit_cast(bf16x8, (u32x4){hu[0],hu[1],hu[2],hu[3]}); \
            al[i] = __builtin_bit_cast(bf16x8, (u32x4){lu[0],lu[1],lu[2],lu[3]}); \
        }                                                                      \
    } while (0)

    #define DOMFMA(b, ah, al) do {                                             \
        _Pragma("unroll")                                                      \
        for (int te = 0; te < 8; ++te) {                                       \
            acc[0][te] = __builtin_amdgcn_mfma_f32_16x16x32_bf16(ah[0], b[te][0], acc[0][te], 0, 0, 0); \
            acc[1][te] = __builtin_amdgcn_mfma_f32_16x16x32_bf16(ah[1], b[te][0], acc[1][te], 0, 0, 0); \
            acc[0][te] = __builtin_amdgcn_mfma_f32_16x16x32_bf16(al[0], b[te][0], acc[0][te], 0, 0, 0); \
            acc[1][te] = __builtin_amdgcn_mfma_f32_16x16x32_bf16(al[1], b[te][0], acc[1][te], 0, 0, 0); \
            acc[0][te] = __builtin_amdgcn_mfma_f32_16x16x32_bf16(ah[0], b[te][1], acc[0][te], 0, 0, 0); \
            acc[1][te] = __builtin_amdgcn_mfma_f32_16x16x32_bf16(ah[1], b[te][1], acc[1][te], 0, 0, 0); \
        }                                                                      \
    } while (0)

    LOADB(b0, 0);
    for (int p = 0; p < 8; ++p) {
        bf16x8 ah[2], al[2];
        LOADB(b1, 2 * p + 1);
        SPLITA(2 * p, ah, al);
        DOMFMA(b0, ah, al);
        if (p < 7) LOADB(b0, 2 * p + 2);
        SPLITA(2 * p + 1, ah, al);
        DOMFMA(b1, ah, al);
    }

    // ---- cross-wave K reduction ----
    if (w < 2) {
        #pragma unroll
        for (int i = 0; i < 2; ++i)
            #pragma unroll
            for (int te = 0; te < 8; ++te)
                #pragma unroll
                for (int q = 0; q < 4; ++q)
                    ps[w][(i * 16 + lhi * 4 + q) * 132 + te * 16 + l15] = acc[i][te][q];
    }
    __syncthreads();
    if (w >= 2) {
        #pragma unroll
        for (int i = 0; i < 2; ++i)
            #pragma unroll
            for (int te = 0; te < 8; ++te)
                #pragma unroll
                for (int q = 0; q < 4; ++q) {
                    int o = (i * 16 + lhi * 4 + q) * 132 + te * 16 + l15;
                    ps[w - 2][o] += acc[i][te][q];
                }
    }
    __syncthreads();
    // fold + coalesced store of raw f32 logits into the out scores region
    #pragma unroll
    for (int q = 0; q < 4; ++q) {
        int i = tid + q * 256;                 // 0..1023
        int row = i >> 5, c4 = i & 31;
        int o = row * 132 + c4 * 4;
        float4 a = *(float4*)&ps[0][o];
        float4 b = *(float4*)&ps[1][o];
        a.x += b.x; a.y += b.y; a.z += b.z; a.w += b.w;
        *(float4*)(outLg + (size_t)(t0 + row) * NE + c4 * 4) = a;
    }
}

// ---------------- K2: wave-per-token parallel top-13 select (no per-thread arrays) ----------------
__global__ __launch_bounds__(256) void select_kernel(
    float* out, unsigned int* __restrict__ ws)
{
    const int lane   = threadIdx.x & 63;
    const int wid    = (blockIdx.x * (blockDim.x >> 6)) + (threadIdx.x >> 6);
    const int nwaves = gridDim.x * (blockDim.x >> 6);

    for (int t = wid; t < NT; t += nwaves) {
        float* row = out + (size_t)t * NE;
        float2 v2 = *(const float2*)(row + lane * 2);
        const float ov0 = v2.x, ov1 = v2.y;
        float v0 = ov0, v1 = ov1;
        const int i0 = lane * 2, i1 = lane * 2 + 1;

        float myv = 0.f; int myi = 0;   // lane k holds rank-k (value, index), k<13
        int r0 = -1, r1 = -1;           // this lane's experts' ranks if in top-8

        #pragma unroll
        for (int k = 0; k < 13; ++k) {
            float av = v0; int ai = i0;
            if (v1 > av) { av = v1; ai = i1; }     // tie keeps lower index i0
            #pragma unroll
            for (int off = 32; off >= 1; off >>= 1) {
                float qv = __shfl_xor(av, off);
                int   qi = __shfl_xor(ai, off);
                if (qv > av || (qv == av && qi < ai)) { av = qv; ai = qi; }
            }
            if (lane == k) { myv = av; myi = ai; }
            if (k < 8) {
                if (i0 == ai) r0 = k;
                if (i1 == ai) r1 = k;
            }
            if (i0 == ai) v0 = -3.0e38f;
            if (i1 == ai) v1 = -3.0e38f;
        }

        // broadcast needed rank values
        const float top0 = __shfl(myv, 0);
        const float v7   = __shfl(myv, 7);
        const float v12  = __shfl(myv, 12);
        const float nv   = __shfl(myv, lane + 1);   // lane k -> rank k+1 value

        // flag: any adjacent gap among ranks 0..8 below 2B
        const bool gap = (lane < 8) && (myv - nv < TWO_B);
        const bool flagged = __any(gap);

        // ksum over ranks 0..7 (tree sum; all lanes end with ksum)
        float pvk = (lane < 8) ? expf(myv - top0) : 0.f;
        float ksum = pvk;
        #pragma unroll
        for (int off = 1; off < 8; off <<= 1) ksum += __shfl_xor(ksum, off);
        ksum = __shfl(ksum, lane & 56);   // lanes 0..7 hold the full sum; take group base
        ksum = __shfl(ksum, 0);

        // build final dense row in registers; single coalesced float2 store
        float o0 = 0.f, o1 = 0.f;
        if (r0 >= 0) o0 = expf(ov0 - top0) / ksum;
        if (r1 >= 0) o1 = expf(ov1 - top0) / ksum;
        *(float2*)(row + lane * 2) = make_float2(o0, o1);

        // indices output (ranks 0..7)
        if (lane < 8)
            out[(size_t)NT * NE + (size_t)t * TOPK + lane] = (float)myi;

        if (flagged) {
            const float thr = v7 - TWO_B;
            unsigned int cnt;
            if (v12 >= thr) {
                cnt = 0xFFu;
            } else {
                bool inc = (lane < 8) || (lane < 13 && myv >= thr);
                cnt = (unsigned int)__popcll(__ballot(inc) & 0x1FFFull);
            }
            unsigned int wrd0 = 0, wrd1 = 0, wrd2 = 0, wrd3 = 0;
            #pragma unroll
            for (int b = 0; b < 4; ++b) {
                unsigned int id;
                id = (unsigned int)__shfl(myi, 0 + b)  & 255u;
                if ((unsigned int)(0 + b)  < cnt) wrd0 |= id << (8 * b);
                id = (unsigned int)__shfl(myi, 4 + b)  & 255u;
                if ((unsigned int)(4 + b)  < cnt) wrd1 |= id << (8 * b);
                id = (unsigned int)__shfl(myi, 8 + b)  & 255u;
                if ((unsigned int)(8 + b)  < cnt && cnt != 0xFFu) wrd2 |= id << (8 * b);
                id = (unsigned int)__shfl(myi, 12 + b) & 255u;
                if ((unsigned int)(12 + b) < cnt && cnt != 0xFFu) wrd3 |= id << (8 * b);
            }
            if (lane == 0) {
                unsigned int slot = atomicAdd(ws, 1u);
                unsigned int* rec = ws + WS_REC_U32 + slot * 8;
                rec[0] = (unsigned int)t;
                rec[1] = cnt;
                rec[2] = wrd0; rec[3] = wrd1; rec[4] = wrd2; rec[5] = wrd3;
            }
        }
    }
}

// ---------------- K3: f64 refine flagged tokens ----------------
__global__ __launch_bounds__(256) void finalize_kernel(
    const float* __restrict__ X, const float* __restrict__ W,
    float* __restrict__ out, const unsigned int* __restrict__ ws)
{
    __shared__ float  xs[2048];
    __shared__ double cv[128];
    __shared__ int    cid[128];
    __shared__ float  ovals[8];
    __shared__ int    oidx[8];

    const int tid = threadIdx.x;
    const int lane = tid & 63, w = tid >> 6;
    const unsigned int n = ws[0];

    for (unsigned int rI = blockIdx.x; rI < n; rI += gridDim.x) {
        const unsigned int* rec = ws + WS_REC_U32 + rI * 8;
        const int tg = (int)rec[0];
        const unsigned int cnt = rec[1];
        const unsigned char* ids = (const unsigned char*)(rec + 2);
        const int nc = (cnt == 0xFFu) ? NE : (int)cnt;

        #pragma unroll
        for (int q = 0; q < 2; ++q) {
            int i = tid + q * 256;
            *(float4*)(xs + i * 4) = *(const float4*)(X + (size_t)tg * NH + i * 4);
        }
        __syncthreads();

        for (int c = w; c < nc; c += 4) {
            int e = (cnt == 0xFFu) ? c : (int)ids[c];
            const float* wrow = W + (size_t)e * NH;
            double s = 0.0;
            #pragma unroll
            for (int m = 0; m < 8; ++m) {
                float4 wv = *(const float4*)(wrow + m * 256 + lane * 4);
                float4 xv = *(const float4*)(xs + m * 256 + lane * 4);
                s = fma((double)xv.x, (double)wv.x, s);
                s = fma((double)xv.y, (double)wv.y, s);
                s = fma((double)xv.z, (double)wv.z, s);
                s = fma((double)xv.w, (double)wv.w, s);
            }
            #pragma unroll
            for (int off = 32; off >= 1; off >>= 1) s += __shfl_xor(s, off);
            if (lane == 0) { cv[c] = s; cid[c] = e; }
        }
        __syncthreads();

        if (tid == 0) {
            double lv[8];
            #pragma unroll
            for (int k = 0; k < 8; ++k) {
                double best = -1.0e300; int bi = 1 << 30, bc = 0;
                for (int c = 0; c < nc; ++c) {
                    double v = cv[c]; int e = cid[c];
                    if (v > best || (v == best && e < bi)) { best = v; bi = e; bc = c; }
                }
                lv[k] = best; oidx[k] = bi; cv[bc] = -1.0e301;
            }
            double m = lv[0], sum = 0.0, p[8];
            #pragma unroll
            for (int k = 0; k < 8; ++k) { p[k] = exp(lv[k] - m); sum += p[k]; }
            #pragma unroll
            for (int k = 0; k < 8; ++k) ovals[k] = (float)(p[k] / sum);
        }
        __syncthreads();

        float* srow = out + (size_t)tg * NE;
        if (tid < NE) {
            float val = 0.f;
            #pragma unroll
            for (int k = 0; k < 8; ++k) if (oidx[k] == tid) val = ovals[k];
            srow[tid] = val;
        }
        if (tid < TOPK) out[(size_t)NT * NE + (size_t)tg * TOPK + tid] = (float)oidx[tid];
        __syncthreads();
    }
}

extern "C" void kernel_launch(void* const* d_in, const int* in_sizes, int n_in,
                              void* d_out, int out_size, void* d_ws, size_t ws_size,
                              hipStream_t stream) {
    const float* X = (const float*)d_in[0];
    const float* W = (const float*)d_in[1];
    float* out = (float*)d_out;
    unsigned char* wsb = (unsigned char*)d_ws;
    unsigned short* Wt = (unsigned short*)(wsb + WS_W_OFF);

    hipMemsetAsync(d_ws, 0, 64, stream);
    prep_w_kernel<<<256, 256, 0, stream>>>(W, Wt);
    router_gemm_kernel<<<NT / BT, 256, 0, stream>>>(X, Wt, out);
    select_kernel<<<2048, 256, 0, stream>>>(out, (unsigned int*)d_ws);
    finalize_kernel<<<1024, 256, 0, stream>>>(X, W, out, (const unsigned int*)d_ws);
}